// Round 6
// baseline (656.436 us; speedup 1.0000x reference)
//
#include <hip/hip_runtime.h>

#define K_ITER   30
#define MU       0.01f
#define EPS      1e-6f
#define MAX_LS   25
#define FULLMASK 0x01FFFFFFu
#define MM       128
#define NN       256
#define NPROB    512
#define NTHR     512          // 8 waves/block; launch_bounds(512,4) -> 2 blocks/CU guaranteed

// ---- ws layout (unsigned words); zero-initialized each launch ----
// flag[p]  : one 128B line per block: ((k+1)<<25) | bad-bits   (written by block p)
// bcast[i] : 16 lines: ((k+1)<<25) | gm                        (written by master)
#define LSTRIDE 32
#define NBC     16
#define W_FLAG(p)  ((p)*LSTRIDE)
#define W_BCAST(i) (NPROB*LSTRIDE + (i)*LSTRIDE)
#define W_END      (NPROB*LSTRIDE + NBC*LSTRIDE)   // 16896 words

// --- cross-lane helpers ---------------------------------------------------
#define RED64_AND(v) do { v &= __shfl_xor(v, 1);  v &= __shfl_xor(v, 2);  v &= __shfl_xor(v, 4); \
                          v &= __shfl_xor(v, 8);  v &= __shfl_xor(v, 16); v &= __shfl_xor(v, 32); } while (0)
#define RED64_OR(v)  do { v |= __shfl_xor(v, 1);  v |= __shfl_xor(v, 2);  v |= __shfl_xor(v, 4); \
                          v |= __shfl_xor(v, 8);  v |= __shfl_xor(v, 16); v |= __shfl_xor(v, 32); } while (0)
#define RED64_MIN(v) do { v = fminf(v, __shfl_xor(v, 1));  v = fminf(v, __shfl_xor(v, 2)); \
                          v = fminf(v, __shfl_xor(v, 4));  v = fminf(v, __shfl_xor(v, 8)); \
                          v = fminf(v, __shfl_xor(v, 16)); v = fminf(v, __shfl_xor(v, 32)); } while (0)

#define AGLOAD(p)     __hip_atomic_load((p),      __ATOMIC_RELAXED, __HIP_MEMORY_SCOPE_AGENT)
#define AGSTORE(p, v) __hip_atomic_store((p), (v), __ATOMIC_RELAXED, __HIP_MEMORY_SCOPE_AGENT)

// DPP circular row_ror reduction: sum over each 16-lane row; every lane of
// the row ends with the full 16-sum (VALU pipe only — no DS traffic).
__device__ __forceinline__ float red16_add(float v) {
    v += __int_as_float(__builtin_amdgcn_update_dpp(0, __float_as_int(v), 0x128, 0xF, 0xF, false)); // ror:8
    v += __int_as_float(__builtin_amdgcn_update_dpp(0, __float_as_int(v), 0x124, 0xF, 0xF, false)); // ror:4
    v += __int_as_float(__builtin_amdgcn_update_dpp(0, __float_as_int(v), 0x122, 0xF, 0xF, false)); // ror:2
    v += __int_as_float(__builtin_amdgcn_update_dpp(0, __float_as_int(v), 0x121, 0xF, 0xF, false)); // ror:1
    return v;
}

// -------------------------------------------------------- ws clear ----
__global__ void lbp_ws_init(unsigned* __restrict__ wsu)
{
    const int idx = blockIdx.x * 1024 + threadIdx.x;
    if (idx < W_END) wsu[idx] = 0u;
}

// Persistent kernel: block p owns problem p; A slice lives in 64 regs/thread.
// Lane (g=lane>>4, j=lane&15) of wave w holds rows 16w+4g+r (r=0..3) and col
// chunks [4j+64c .. 4j+64c+3] (c=0..3).  Row state (bb/ce/cl/axc/pg/px) is
// register-resident (row ownership identical in both passes).  16-lane
// reduces use DPP row_ror (VALU).  m-side line-search is fused into pass 2
// via dual wave ballots.  4 __syncthreads per iteration.
__global__ __launch_bounds__(NTHR, 4)
void lbp_fused(const float* __restrict__ xraw_g,
               const float* __restrict__ A_g,
               const float* __restrict__ b_g,
               const float* __restrict__ lower_g,
               float* __restrict__ out_g,
               unsigned* __restrict__ wsu)
{
    const int p    = blockIdx.x;
    const int t    = threadIdx.x;
    const int lane = t & 63;
    const int wave = t >> 6;          // 0..7
    const int g    = lane >> 4;       // 0..3  row sub-group
    const int j    = lane & 15;       // 0..15 col sub-group
    const int wb   = wave * 16;       // wave's base row

    const float* A = A_g + (size_t)p * (MM * NN);

    __shared__ __align__(16) float s_x[NN];
    __shared__ __align__(16) float s_grad[NN];
    __shared__ __align__(16) float s_xraw[NN];
    __shared__ __align__(16) float s_lower[NN];
    __shared__ __align__(16) float s_p1g[32][NN];          // per-(wave,g) A^T w partials
    __shared__ float s_redw[8];
    __shared__ unsigned s_redu[8];
    __shared__ unsigned s_mask, s_gm;
    __shared__ float s_step, s_t0;

    // ---- load A slice into registers (only HBM read of A in the solve) ----
    float4 a[4][4];
    {
        const float* base = A + (size_t)(wb + 4 * g) * NN + 4 * j;
        #pragma unroll
        for (int r = 0; r < 4; ++r)
            #pragma unroll
            for (int c = 0; c < 4; ++c)
                a[r][c] = *(const float4*)(base + r * NN + 64 * c);
    }

    if (t < NN) { s_xraw[t] = xraw_g[p * NN + t]; s_lower[t] = lower_g[p * NN + t]; }

    float bbr[4];
    #pragma unroll
    for (int r = 0; r < 4; ++r) bbr[r] = b_g[p * MM + wb + 4 * g + r];

    // per-lane line-search step constants (step_l = 2^-l)
    const float stepj0 = ldexpf(1.0f, -j);
    const float stepj1 = ldexpf(1.0f, -(j + 16));   // meaningful for j < 9

    if (t == 0) s_mask = 0xFFFFFFFFu;
    __syncthreads();

    // ---- init: row stats (ssq, rowsum, A·lower) from registers ----
    float cer[4], clr[4], axcr[4];
    {
        float ssq[4] = {0.f,0.f,0.f,0.f}, rs[4] = {0.f,0.f,0.f,0.f}, al[4] = {0.f,0.f,0.f,0.f};
        #pragma unroll
        for (int c = 0; c < 4; ++c) {
            const float4 lo4 = ((const float4*)s_lower)[j + 16 * c];
            #pragma unroll
            for (int r = 0; r < 4; ++r) {
                const float4 av = a[r][c];
                ssq[r] += av.x*av.x + av.y*av.y + av.z*av.z + av.w*av.w;
                rs[r]  += av.x + av.y + av.z + av.w;
                al[r]  += av.x*lo4.x + av.y*lo4.y + av.z*lo4.z + av.w*lo4.w;
            }
        }
        float alr[4], rsr[4];
        float rmin = INFINITY;
        #pragma unroll
        for (int r = 0; r < 4; ++r) {
            const float ssqs = red16_add(ssq[r]);
            const float rss  = red16_add(rs[r]);
            const float als  = red16_add(al[r]);
            const float rr = fmaxf(sqrtf(ssqs), 1e-12f);
            clr[r] = 1e-12f * rr;                    // slack clamp (unnormalized)
            cer[r] = bbr[r] - EPS * rr;              // feasibility threshold
            const float adw = rss / rr;
            const float sw  = (bbr[r] - als) / rr;
            const float ratio = (adw > 0.f) ? (sw / fmaxf(adw, 1e-12f)) : INFINITY;
            rmin = fminf(rmin, ratio);
            alr[r] = als; rsr[r] = rss;
        }
        RED64_MIN(rmin);
        if (lane == 0) s_redw[wave] = rmin;
        __syncthreads();
        if (t == 0) {
            float m = s_redw[0];
            #pragma unroll
            for (int w = 1; w < 8; ++w) m = fminf(m, s_redw[w]);
            s_t0 = fmaxf(0.5f * m, 2.0f * EPS);
        }
        __syncthreads();
        const float t0v = s_t0;
        if (t < NN) s_x[t] = s_lower[t] + t0v;
        #pragma unroll
        for (int r = 0; r < 4; ++r) axcr[r] = alr[r] + t0v * rsr[r];
    }

    // feasibility repair (faithful to module; no-op for these inputs)
    {
        int okf = 1;
        #pragma unroll
        for (int r = 0; r < 4; ++r) okf = okf && (axcr[r] <= cer[r]);
        if (t < NN) okf = okf && (s_x[t] >= s_lower[t] + EPS);
        const int feas = __syncthreads_and(okf);
        if (!feas) {
            if (t < NN) s_x[t] = 0.5f * (fmaxf(s_x[t], 0.f) + s_lower[t]);
            __syncthreads();
            float axp[4] = {0.f,0.f,0.f,0.f};
            #pragma unroll
            for (int c = 0; c < 4; ++c) {
                const float4 x4 = ((const float4*)s_x)[j + 16 * c];
                #pragma unroll
                for (int r = 0; r < 4; ++r) {
                    const float4 av = a[r][c];
                    axp[r] += av.x*x4.x + av.y*x4.y + av.z*x4.z + av.w*x4.w;
                }
            }
            #pragma unroll
            for (int r = 0; r < 4; ++r) axcr[r] = red16_add(axp[r]);
        }
    }

    // ------------------------------ main loop ------------------------------
    float pgr[4], pxr[4];
    for (int k = 0; k < K_ITER; ++k) {
        // barrier weights for owned rows (registers, no LDS phase)
        float wm[4];
        #pragma unroll
        for (int r = 0; r < 4; ++r) wm[r] = MU / fmaxf(bbr[r] - axcr[r], clr[r]);

        // pass 1: gbar = A^T w — per-(wave,g) partials straight to LDS
        {
            float4 gb[4];
            #pragma unroll
            for (int c = 0; c < 4; ++c) gb[c] = make_float4(0.f, 0.f, 0.f, 0.f);
            #pragma unroll
            for (int r = 0; r < 4; ++r) {
                const float wmr = wm[r];
                #pragma unroll
                for (int c = 0; c < 4; ++c) {
                    gb[c].x += a[r][c].x * wmr;
                    gb[c].y += a[r][c].y * wmr;
                    gb[c].z += a[r][c].z * wmr;
                    gb[c].w += a[r][c].w * wmr;
                }
            }
            #pragma unroll
            for (int c = 0; c < 4; ++c)
                ((float4*)s_p1g[wave * 4 + g])[j + 16 * c] = gb[c];
        }
        __syncthreads();                                   // sync1

        // grad + n-side line-search mask (waves 0-3)
        if (t < NN) {
            float gsum = 0.f;
            #pragma unroll
            for (int q = 0; q < 32; ++q) gsum += s_p1g[q][t];
            const float xt = s_x[t];
            const float gr = (xt - s_xraw[t]) + gsum + MU / fmaxf(xt - s_lower[t], 1e-12f);
            s_grad[t] = gr;
            unsigned mn = 0u;
            const float loe = s_lower[t] + EPS;
            float st = 1.0f;
            #pragma unroll
            for (int l = 0; l < MAX_LS; ++l) {
                if (xt - st * gr >= loe) mn |= (1u << l);
                st *= 0.5f;
            }
            RED64_AND(mn);
            if (lane == 0) atomicAnd(&s_mask, mn);
        }
        __syncthreads();                                   // sync2

        // pass 2: pg = A*grad, px = A*x + fused m-side line-search mask
        {
            float pg[4] = {0.f,0.f,0.f,0.f}, px[4] = {0.f,0.f,0.f,0.f};
            #pragma unroll
            for (int c = 0; c < 4; ++c) {
                const float4 g4 = ((const float4*)s_grad)[j + 16 * c];
                const float4 x4 = ((const float4*)s_x)[j + 16 * c];
                #pragma unroll
                for (int r = 0; r < 4; ++r) {
                    const float4 av = a[r][c];
                    pg[r] += av.x*g4.x + av.y*g4.y + av.z*g4.z + av.w*g4.w;
                    px[r] += av.x*x4.x + av.y*x4.y + av.z*x4.z + av.w*x4.w;
                }
            }
            unsigned mand = 0xFFFFFFFFu;
            #pragma unroll
            for (int r = 0; r < 4; ++r) {
                const float pgs = red16_add(pg[r]);        // all 16 lanes get row sum
                const float pxs = red16_add(px[r]);
                pgr[r] = pgs; pxr[r] = pxs;
                const bool ok0 = (pxs - stepj0 * pgs) <= cer[r];   // step j
                const bool ok1 = (pxs - stepj1 * pgs) <= cer[r];   // step j+16
                const unsigned long long b0 = __ballot(ok0);
                const unsigned long long b1 = __ballot(ok1);
                const unsigned f = ((unsigned)(b0 >> (16 * g)) & 0xFFFFu)
                                 | (((unsigned)(b1 >> (16 * g)) & 0x1FFu) << 16);
                mand &= (f | 0xFE000000u);
            }
            mand &= __shfl_xor(mand, 16);
            mand &= __shfl_xor(mand, 32);
            if (lane == 0) atomicAnd(&s_mask, mand);
        }
        __syncthreads();                                   // sync3 (s_mask final)

        // ---- grid consensus: flag-store + master OR-reduce + broadcast ----
        const unsigned tag = (unsigned)(k + 1) << 25;
        if (p == 0) {
            unsigned bad;
            if (t == 0) {
                bad = (~s_mask) & FULLMASK;
            } else {
                unsigned v;
                while ((((v = AGLOAD(&wsu[W_FLAG(t)])) >> 25)) != (unsigned)(k + 1))
                    __builtin_amdgcn_s_sleep(1);
                bad = v & FULLMASK;
            }
            RED64_OR(bad);
            if (lane == 0) s_redu[wave] = bad;
            __syncthreads();
            if (t == 0) {
                unsigned orall = 0u;
                #pragma unroll
                for (int w = 0; w < 8; ++w) orall |= s_redu[w];
                const unsigned gm = FULLMASK & ~orall;
                s_gm   = gm;
                s_step = gm ? ldexpf(1.0f, -(__ffs(gm) - 1)) : 0.0f;
                s_mask = 0xFFFFFFFFu;                      // re-arm for next iter
            }
            __syncthreads();                               // sync4 (master)
            if (t < NBC) AGSTORE(&wsu[W_BCAST(t)], tag | s_gm);
        } else {
            if (t == 0) {
                AGSTORE(&wsu[W_FLAG(p)], tag | ((~s_mask) & FULLMASK));
                s_mask = 0xFFFFFFFFu;                      // re-arm for next iter
                unsigned v;
                while ((((v = AGLOAD(&wsu[W_BCAST(p & (NBC - 1))])) >> 25)) != (unsigned)(k + 1))
                    __builtin_amdgcn_s_sleep(1);
                const unsigned gm = v & FULLMASK;
                s_step = gm ? ldexpf(1.0f, -(__ffs(gm) - 1)) : 0.0f;
            }
            __syncthreads();                               // sync4
        }

        const float step = s_step;
        if (t < NN) s_x[t] -= step * s_grad[t];
        #pragma unroll
        for (int r = 0; r < 4; ++r) axcr[r] = pxr[r] - step * pgr[r];
        // no loop-top sync needed: s_p1g last read before sync2; s_x cross-
        // thread reads (pass 2) are beyond sync1+sync2 of the next iteration.
    }

    if (t < NN) out_g[p * NN + t] = fmaxf(s_x[t], 0.0f);
}

// -------------------------------------------------------------- launch ----
extern "C" void kernel_launch(void* const* d_in, const int* in_sizes, int n_in,
                              void* d_out, int out_size, void* d_ws, size_t ws_size,
                              hipStream_t stream) {
    const float* xraw  = (const float*)d_in[0];
    const float* A     = (const float*)d_in[1];
    const float* b     = (const float*)d_in[2];
    const float* lower = (const float*)d_in[3];
    float* out = (float*)d_out;
    unsigned* wsu = (unsigned*)d_ws;

    lbp_ws_init<<<(W_END + 1023) / 1024, 1024, 0, stream>>>(wsu);
    lbp_fused<<<NPROB, NTHR, 0, stream>>>(xraw, A, b, lower, out, wsu);
}

// Round 7
// 270.542 us; speedup vs baseline: 2.4264x; 2.4264x over previous
//
#include <hip/hip_runtime.h>

#define K_ITER   30
#define MU       0.01f
#define EPS      1e-6f
#define MAX_LS   25
#define FULLMASK 0x01FFFFFFu
#define MM       128
#define NN       256
#define NPROB    512
#define NTHR     512          // 8 waves/block; launch_bounds(512,4) -> 2 blocks/CU guaranteed

// ---- ws layout (unsigned words); zero-initialized each launch ----
// flag[p]  : one 128B line per block: ((k+1)<<25) | bad-bits   (written by block p)
// bcast[i] : 16 lines: ((k+1)<<25) | gm                        (written by master)
#define LSTRIDE 32
#define NBC     16
#define W_FLAG(p)  ((p)*LSTRIDE)
#define W_BCAST(i) (NPROB*LSTRIDE + (i)*LSTRIDE)
#define W_END      (NPROB*LSTRIDE + NBC*LSTRIDE)   // 16896 words

// --- cross-lane helpers ---------------------------------------------------
#define RED64_AND(v) do { v &= __shfl_xor(v, 1);  v &= __shfl_xor(v, 2);  v &= __shfl_xor(v, 4); \
                          v &= __shfl_xor(v, 8);  v &= __shfl_xor(v, 16); v &= __shfl_xor(v, 32); } while (0)
#define RED64_OR(v)  do { v |= __shfl_xor(v, 1);  v |= __shfl_xor(v, 2);  v |= __shfl_xor(v, 4); \
                          v |= __shfl_xor(v, 8);  v |= __shfl_xor(v, 16); v |= __shfl_xor(v, 32); } while (0)
#define RED64_MIN(v) do { v = fminf(v, __shfl_xor(v, 1));  v = fminf(v, __shfl_xor(v, 2)); \
                          v = fminf(v, __shfl_xor(v, 4));  v = fminf(v, __shfl_xor(v, 8)); \
                          v = fminf(v, __shfl_xor(v, 16)); v = fminf(v, __shfl_xor(v, 32)); } while (0)

#define AGLOAD(p)     __hip_atomic_load((p),      __ATOMIC_RELAXED, __HIP_MEMORY_SCOPE_AGENT)
#define AGSTORE(p, v) __hip_atomic_store((p), (v), __ATOMIC_RELAXED, __HIP_MEMORY_SCOPE_AGENT)

// DPP circular row_ror reduction: sum over each 16-lane group; every lane of
// the group ends with the full 16-sum (VALU pipe only — no DS traffic).
__device__ __forceinline__ float red16_add(float v) {
    v += __int_as_float(__builtin_amdgcn_update_dpp(0, __float_as_int(v), 0x128, 0xF, 0xF, false)); // ror:8
    v += __int_as_float(__builtin_amdgcn_update_dpp(0, __float_as_int(v), 0x124, 0xF, 0xF, false)); // ror:4
    v += __int_as_float(__builtin_amdgcn_update_dpp(0, __float_as_int(v), 0x122, 0xF, 0xF, false)); // ror:2
    v += __int_as_float(__builtin_amdgcn_update_dpp(0, __float_as_int(v), 0x121, 0xF, 0xF, false)); // ror:1
    return v;
}

// -------------------------------------------------------- ws clear ----
__global__ void lbp_ws_init(unsigned* __restrict__ wsu)
{
    const int idx = blockIdx.x * 1024 + threadIdx.x;
    if (idx < W_END) wsu[idx] = 0u;
}

// Persistent kernel: block p owns problem p; A slice lives in 64 regs/thread
// (AGPR half of the unified file).  Lane (g=lane>>4, j=lane&15) of wave w
// holds rows 16w+4g+r (r=0..3) and col chunks [4j+64c..+3] (c=0..3).
// Register budget is the hard constraint: 2 blocks/CU co-residency -> 4
// waves/SIMD -> 128 unified regs/thread.  A=64 AGPR; keep VGPR peak < 64:
// row state pg/px lives in LDS (j==0 stores), only loop-invariant bb/ce/cl
// are register-resident.  axc never materializes: pass 1 reconstructs it as
// s_px - s_step*s_pg (identical fp expression to the R5/R6 epilogue).
__global__ __launch_bounds__(NTHR, 4)
void lbp_fused(const float* __restrict__ xraw_g,
               const float* __restrict__ A_g,
               const float* __restrict__ b_g,
               const float* __restrict__ lower_g,
               float* __restrict__ out_g,
               unsigned* __restrict__ wsu)
{
    const int p    = blockIdx.x;
    const int t    = threadIdx.x;
    const int lane = t & 63;
    const int wave = t >> 6;          // 0..7
    const int g    = lane >> 4;       // 0..3  row sub-group
    const int j    = lane & 15;       // 0..15 col sub-group
    const int wb   = wave * 16;       // wave's base row

    const float* A = A_g + (size_t)p * (MM * NN);

    __shared__ __align__(16) float s_x[NN];
    __shared__ __align__(16) float s_grad[NN];
    __shared__ __align__(16) float s_xraw[NN];
    __shared__ __align__(16) float s_lower[NN];
    __shared__ __align__(16) float s_p1g[32][NN];          // per-(wave,g) A^T w partials
    __shared__ float s_pg[MM], s_px[MM];                   // row state (j==0 writes)
    __shared__ float s_redw[8];
    __shared__ unsigned s_redu[8];
    __shared__ unsigned s_mask, s_gm;
    __shared__ float s_step, s_t0;

    // ---- load A slice into registers (only HBM read of A in the solve) ----
    float4 a[4][4];
    {
        const float* base = A + (size_t)(wb + 4 * g) * NN + 4 * j;
        #pragma unroll
        for (int r = 0; r < 4; ++r)
            #pragma unroll
            for (int c = 0; c < 4; ++c)
                a[r][c] = *(const float4*)(base + r * NN + 64 * c);
    }

    if (t < NN) { s_xraw[t] = xraw_g[p * NN + t]; s_lower[t] = lower_g[p * NN + t]; }

    float bbr[4];
    #pragma unroll
    for (int r = 0; r < 4; ++r) bbr[r] = b_g[p * MM + wb + 4 * g + r];

    const float stepj0 = ldexpf(1.0f, -j);   // line-search step 2^-j for this lane

    if (t == 0) { s_mask = 0xFFFFFFFFu; s_step = 0.0f; }
    __syncthreads();

    // ---- init: row stats (ssq, rowsum, A·lower) from registers ----
    float cer[4], clr[4];
    {
        float ssq[4] = {0.f,0.f,0.f,0.f}, rs[4] = {0.f,0.f,0.f,0.f}, al[4] = {0.f,0.f,0.f,0.f};
        #pragma unroll
        for (int c = 0; c < 4; ++c) {
            const float4 lo4 = ((const float4*)s_lower)[j + 16 * c];
            #pragma unroll
            for (int r = 0; r < 4; ++r) {
                const float4 av = a[r][c];
                ssq[r] += av.x*av.x + av.y*av.y + av.z*av.z + av.w*av.w;
                rs[r]  += av.x + av.y + av.z + av.w;
                al[r]  += av.x*lo4.x + av.y*lo4.y + av.z*lo4.z + av.w*lo4.w;
            }
        }
        float alr[4], rsr[4];
        float rmin = INFINITY;
        #pragma unroll
        for (int r = 0; r < 4; ++r) {
            const float ssqs = red16_add(ssq[r]);
            const float rss  = red16_add(rs[r]);
            const float als  = red16_add(al[r]);
            const float rr = fmaxf(sqrtf(ssqs), 1e-12f);
            clr[r] = 1e-12f * rr;                    // slack clamp (unnormalized)
            cer[r] = bbr[r] - EPS * rr;              // feasibility threshold
            const float adw = rss / rr;
            const float sw  = (bbr[r] - als) / rr;
            const float ratio = (adw > 0.f) ? (sw / fmaxf(adw, 1e-12f)) : INFINITY;
            rmin = fminf(rmin, ratio);
            alr[r] = als; rsr[r] = rss;
        }
        RED64_MIN(rmin);
        if (lane == 0) s_redw[wave] = rmin;
        __syncthreads();
        if (t == 0) {
            float m = s_redw[0];
            #pragma unroll
            for (int w = 1; w < 8; ++w) m = fminf(m, s_redw[w]);
            s_t0 = fmaxf(0.5f * m, 2.0f * EPS);
        }
        __syncthreads();
        const float t0v = s_t0;
        float xi = 0.f;
        if (t < NN) { xi = s_lower[t] + t0v; s_x[t] = xi; }
        float axc0[4];
        #pragma unroll
        for (int r = 0; r < 4; ++r) {
            axc0[r] = alr[r] + t0v * rsr[r];
            if (j == 0) { s_px[wb + 4 * g + r] = axc0[r]; s_pg[wb + 4 * g + r] = 0.f; }
        }

        // feasibility repair (faithful to module; no-op for these inputs)
        int okf = 1;
        #pragma unroll
        for (int r = 0; r < 4; ++r) okf = okf && (axc0[r] <= cer[r]);
        if (t < NN) okf = okf && (xi >= s_lower[t] + EPS);
        const int feas = __syncthreads_and(okf);
        if (!feas) {
            if (t < NN) s_x[t] = 0.5f * (fmaxf(s_x[t], 0.f) + s_lower[t]);
            __syncthreads();
            float axp[4] = {0.f,0.f,0.f,0.f};
            #pragma unroll
            for (int c = 0; c < 4; ++c) {
                const float4 x4 = ((const float4*)s_x)[j + 16 * c];
                #pragma unroll
                for (int r = 0; r < 4; ++r) {
                    const float4 av = a[r][c];
                    axp[r] += av.x*x4.x + av.y*x4.y + av.z*x4.z + av.w*x4.w;
                }
            }
            #pragma unroll
            for (int r = 0; r < 4; ++r) {
                const float s = red16_add(axp[r]);
                if (j == 0) s_px[wb + 4 * g + r] = s;     // s_pg stays 0
            }
            __syncthreads();
        }
    }

    // ------------------------------ main loop ------------------------------
    for (int k = 0; k < K_ITER; ++k) {
        // pass 1: reconstruct axc, barrier weights, gbar partials.
        // (s_px/s_pg written before prev sync4/init barrier; s_step likewise)
        {
            const float stp = s_step;
            float wm[4];
            #pragma unroll
            for (int r = 0; r < 4; ++r) {
                const int m = wb + 4 * g + r;
                const float axm = s_px[m] - stp * s_pg[m];
                wm[r] = MU / fmaxf(bbr[r] - axm, clr[r]);
            }
            #pragma unroll
            for (int c = 0; c < 4; ++c) {
                float4 gb;
                gb.x = a[0][c].x*wm[0] + a[1][c].x*wm[1] + a[2][c].x*wm[2] + a[3][c].x*wm[3];
                gb.y = a[0][c].y*wm[0] + a[1][c].y*wm[1] + a[2][c].y*wm[2] + a[3][c].y*wm[3];
                gb.z = a[0][c].z*wm[0] + a[1][c].z*wm[1] + a[2][c].z*wm[2] + a[3][c].z*wm[3];
                gb.w = a[0][c].w*wm[0] + a[1][c].w*wm[1] + a[2][c].w*wm[2] + a[3][c].w*wm[3];
                ((float4*)s_p1g[wave * 4 + g])[j + 16 * c] = gb;
            }
        }
        __syncthreads();                                   // sync1

        // grad + n-side line-search mask (waves 0-3)
        if (t < NN) {
            float gsum = 0.f;
            #pragma unroll
            for (int q = 0; q < 32; ++q) gsum += s_p1g[q][t];
            const float xt = s_x[t];
            const float gr = (xt - s_xraw[t]) + gsum + MU / fmaxf(xt - s_lower[t], 1e-12f);
            s_grad[t] = gr;
            unsigned mn = 0u;
            const float loe = s_lower[t] + EPS;
            float st = 1.0f;
            #pragma unroll
            for (int l = 0; l < MAX_LS; ++l) {
                if (xt - st * gr >= loe) mn |= (1u << l);
                st *= 0.5f;
            }
            RED64_AND(mn);
            if (lane == 0) atomicAnd(&s_mask, mn);
        }
        __syncthreads();                                   // sync2

        // pass 2: pg = A*grad, px = A*x + fused m-side line-search ballots
        {
            float pg[4] = {0.f,0.f,0.f,0.f}, px[4] = {0.f,0.f,0.f,0.f};
            #pragma unroll
            for (int c = 0; c < 4; ++c) {
                const float4 g4 = ((const float4*)s_grad)[j + 16 * c];
                const float4 x4 = ((const float4*)s_x)[j + 16 * c];
                #pragma unroll
                for (int r = 0; r < 4; ++r) {
                    const float4 av = a[r][c];
                    pg[r] += av.x*g4.x + av.y*g4.y + av.z*g4.z + av.w*g4.w;
                    px[r] += av.x*x4.x + av.y*x4.y + av.z*x4.z + av.w*x4.w;
                }
            }
            unsigned mand = 0xFFFFFFFFu;
            #pragma unroll
            for (int r = 0; r < 4; ++r) {
                const float pgs = red16_add(pg[r]);        // all 16 lanes get row sums
                const float pxs = red16_add(px[r]);
                if (j == 0) { s_pg[wb + 4 * g + r] = pgs; s_px[wb + 4 * g + r] = pxs; }
                const bool ok0 = (pxs - stepj0 * pgs) <= cer[r];              // step j
                const bool ok1 = (pxs - (stepj0 * 0x1p-16f) * pgs) <= cer[r]; // step j+16
                const unsigned long long b0 = __ballot(ok0);
                const unsigned long long b1 = __ballot(ok1);
                const unsigned f = ((unsigned)(b0 >> (16 * g)) & 0xFFFFu)
                                 | (((unsigned)(b1 >> (16 * g)) & 0x1FFu) << 16);
                mand &= (f | 0xFE000000u);
            }
            mand &= __shfl_xor(mand, 16);
            mand &= __shfl_xor(mand, 32);
            if (lane == 0) atomicAnd(&s_mask, mand);
        }
        __syncthreads();                                   // sync3 (s_mask final)

        // ---- grid consensus: flag-store + master OR-reduce + broadcast ----
        const unsigned tag = (unsigned)(k + 1) << 25;
        if (p == 0) {
            unsigned bad;
            if (t == 0) {
                bad = (~s_mask) & FULLMASK;
            } else {
                unsigned v;
                while ((((v = AGLOAD(&wsu[W_FLAG(t)])) >> 25)) != (unsigned)(k + 1))
                    __builtin_amdgcn_s_sleep(1);
                bad = v & FULLMASK;
            }
            RED64_OR(bad);
            if (lane == 0) s_redu[wave] = bad;
            __syncthreads();
            if (t == 0) {
                unsigned orall = 0u;
                #pragma unroll
                for (int w = 0; w < 8; ++w) orall |= s_redu[w];
                const unsigned gm = FULLMASK & ~orall;
                s_gm   = gm;
                s_step = gm ? ldexpf(1.0f, -(__ffs(gm) - 1)) : 0.0f;
                s_mask = 0xFFFFFFFFu;                      // re-arm for next iter
            }
            __syncthreads();                               // sync4 (master)
            if (t < NBC) AGSTORE(&wsu[W_BCAST(t)], tag | s_gm);
        } else {
            if (t == 0) {
                AGSTORE(&wsu[W_FLAG(p)], tag | ((~s_mask) & FULLMASK));
                s_mask = 0xFFFFFFFFu;                      // re-arm for next iter
                unsigned v;
                while ((((v = AGLOAD(&wsu[W_BCAST(p & (NBC - 1))])) >> 25)) != (unsigned)(k + 1))
                    __builtin_amdgcn_s_sleep(1);
                const unsigned gm = v & FULLMASK;
                s_step = gm ? ldexpf(1.0f, -(__ffs(gm) - 1)) : 0.0f;
            }
            __syncthreads();                               // sync4
        }

        // epilogue: x update only (axc reconstructed in next pass 1)
        if (t < NN) s_x[t] -= s_step * s_grad[t];
        // ordering: s_x writes -> next sync1 -> grad reads; s_pg/s_px writes
        // (pass2, before sync3) -> next pass1 reads (after sync4).  s_step
        // written before sync4, read here and at next pass1 top, overwritten
        // only after next sync3.
    }

    if (t < NN) out_g[p * NN + t] = fmaxf(s_x[t], 0.0f);
}

// -------------------------------------------------------------- launch ----
extern "C" void kernel_launch(void* const* d_in, const int* in_sizes, int n_in,
                              void* d_out, int out_size, void* d_ws, size_t ws_size,
                              hipStream_t stream) {
    const float* xraw  = (const float*)d_in[0];
    const float* A     = (const float*)d_in[1];
    const float* b     = (const float*)d_in[2];
    const float* lower = (const float*)d_in[3];
    float* out = (float*)d_out;
    unsigned* wsu = (unsigned*)d_ws;

    lbp_ws_init<<<(W_END + 1023) / 1024, 1024, 0, stream>>>(wsu);
    lbp_fused<<<NPROB, NTHR, 0, stream>>>(xraw, A, b, lower, out, wsu);
}

// Round 8
// 240.566 us; speedup vs baseline: 2.7287x; 1.1246x over previous
//
#include <hip/hip_runtime.h>

#define K_ITER   30
#define MU       0.01f
#define EPS      1e-6f
#define MAX_LS   25
#define FULLMASK 0x01FFFFFFu
#define MM       128
#define NN       256
#define NPROB    512
#define NTHR     512          // 8 waves/block; launch_bounds(512,4) -> 2 blocks/CU guaranteed

// ---- ws layout (unsigned words); zero-initialized each launch ----
// flag[p]  : one 128B line per block: ((k+1)<<25) | bad-bits   (written by block p)
// bcast[i] : 16 lines: ((k+1)<<25) | gm                        (written by master t0)
#define LSTRIDE 32
#define NBC     16
#define W_FLAG(p)  ((p)*LSTRIDE)
#define W_BCAST(i) (NPROB*LSTRIDE + (i)*LSTRIDE)
#define W_END      (NPROB*LSTRIDE + NBC*LSTRIDE)   // 16896 words

// --- cross-lane helpers ---------------------------------------------------
#define RED64_AND(v) do { v &= __shfl_xor(v, 1);  v &= __shfl_xor(v, 2);  v &= __shfl_xor(v, 4); \
                          v &= __shfl_xor(v, 8);  v &= __shfl_xor(v, 16); v &= __shfl_xor(v, 32); } while (0)
#define RED64_OR(v)  do { v |= __shfl_xor(v, 1);  v |= __shfl_xor(v, 2);  v |= __shfl_xor(v, 4); \
                          v |= __shfl_xor(v, 8);  v |= __shfl_xor(v, 16); v |= __shfl_xor(v, 32); } while (0)
#define RED64_MIN(v) do { v = fminf(v, __shfl_xor(v, 1));  v = fminf(v, __shfl_xor(v, 2)); \
                          v = fminf(v, __shfl_xor(v, 4));  v = fminf(v, __shfl_xor(v, 8)); \
                          v = fminf(v, __shfl_xor(v, 16)); v = fminf(v, __shfl_xor(v, 32)); } while (0)

#define AGLOAD(p)     __hip_atomic_load((p),      __ATOMIC_RELAXED, __HIP_MEMORY_SCOPE_AGENT)
#define AGSTORE(p, v) __hip_atomic_store((p), (v), __ATOMIC_RELAXED, __HIP_MEMORY_SCOPE_AGENT)

// DPP circular row_ror reduction: sum over each 16-lane group; every lane of
// the group ends with the full 16-sum (VALU pipe only — no DS traffic).
__device__ __forceinline__ float red16_add(float v) {
    v += __int_as_float(__builtin_amdgcn_update_dpp(0, __float_as_int(v), 0x128, 0xF, 0xF, false)); // ror:8
    v += __int_as_float(__builtin_amdgcn_update_dpp(0, __float_as_int(v), 0x124, 0xF, 0xF, false)); // ror:4
    v += __int_as_float(__builtin_amdgcn_update_dpp(0, __float_as_int(v), 0x122, 0xF, 0xF, false)); // ror:2
    v += __int_as_float(__builtin_amdgcn_update_dpp(0, __float_as_int(v), 0x121, 0xF, 0xF, false)); // ror:1
    return v;
}

// -------------------------------------------------------- ws clear ----
__global__ void lbp_ws_init(unsigned* __restrict__ wsu)
{
    const int idx = blockIdx.x * 1024 + threadIdx.x;
    if (idx < W_END) wsu[idx] = 0u;
}

// Persistent kernel: block p owns problem p; A slice lives in 64 regs/thread
// (AGPR half of the unified file; hard budget 128/thread for 2 blocks/CU).
// Lane (g=lane>>4, j=lane&15) of wave w holds rows 16w+4g+r and col chunks
// [4j+64c..+3].  Row state ax/pg lives in LDS; ax is maintained by the
// recurrence ax_k = ax_{k-1} - step*pg (same expression R5-R7 used for the
// barrier weights) — no fresh A*x product anywhere in the loop, so pass 2
// is pg-only.  Grad phase is pair-split across all 8 waves.
__global__ __launch_bounds__(NTHR, 4)
void lbp_fused(const float* __restrict__ xraw_g,
               const float* __restrict__ A_g,
               const float* __restrict__ b_g,
               const float* __restrict__ lower_g,
               float* __restrict__ out_g,
               unsigned* __restrict__ wsu)
{
    const int p    = blockIdx.x;
    const int t    = threadIdx.x;
    const int lane = t & 63;
    const int wave = t >> 6;          // 0..7
    const int g    = lane >> 4;       // 0..3  row sub-group
    const int j    = lane & 15;       // 0..15 col sub-group
    const int wb   = wave * 16;       // wave's base row

    const float* A = A_g + (size_t)p * (MM * NN);

    __shared__ __align__(16) float s_x[NN];
    __shared__ __align__(16) float s_grad[NN];
    __shared__ __align__(16) float s_xraw[NN];
    __shared__ __align__(16) float s_lower[NN];
    __shared__ __align__(16) float s_p1g[32][NN];          // per-(wave,g) A^T w partials
    __shared__ float s_ax[MM], s_pg[MM];                   // row state (j==0 writes)
    __shared__ float s_redw[8];
    __shared__ unsigned s_redu[8];
    __shared__ unsigned s_mask;
    __shared__ float s_step, s_t0;

    // ---- load A slice into registers (only HBM read of A in the solve) ----
    float4 a[4][4];
    {
        const float* base = A + (size_t)(wb + 4 * g) * NN + 4 * j;
        #pragma unroll
        for (int r = 0; r < 4; ++r)
            #pragma unroll
            for (int c = 0; c < 4; ++c)
                a[r][c] = *(const float4*)(base + r * NN + 64 * c);
    }

    if (t < NN) { s_xraw[t] = xraw_g[p * NN + t]; s_lower[t] = lower_g[p * NN + t]; }

    float bbr[4];
    #pragma unroll
    for (int r = 0; r < 4; ++r) bbr[r] = b_g[p * MM + wb + 4 * g + r];

    const float stepj0 = ldexpf(1.0f, -j);   // line-search step 2^-j for this lane

    if (t == 0) { s_mask = 0xFFFFFFFFu; s_step = 0.0f; }
    __syncthreads();

    // ---- init: row stats (ssq, rowsum, A·lower) from registers ----
    float cer[4], clr[4];
    {
        float ssq[4] = {0.f,0.f,0.f,0.f}, rs[4] = {0.f,0.f,0.f,0.f}, al[4] = {0.f,0.f,0.f,0.f};
        #pragma unroll
        for (int c = 0; c < 4; ++c) {
            const float4 lo4 = ((const float4*)s_lower)[j + 16 * c];
            #pragma unroll
            for (int r = 0; r < 4; ++r) {
                const float4 av = a[r][c];
                ssq[r] += av.x*av.x + av.y*av.y + av.z*av.z + av.w*av.w;
                rs[r]  += av.x + av.y + av.z + av.w;
                al[r]  += av.x*lo4.x + av.y*lo4.y + av.z*lo4.z + av.w*lo4.w;
            }
        }
        float alr[4], rsr[4];
        float rmin = INFINITY;
        #pragma unroll
        for (int r = 0; r < 4; ++r) {
            const float ssqs = red16_add(ssq[r]);
            const float rss  = red16_add(rs[r]);
            const float als  = red16_add(al[r]);
            const float rr = fmaxf(sqrtf(ssqs), 1e-12f);
            clr[r] = 1e-12f * rr;                    // slack clamp (unnormalized)
            cer[r] = bbr[r] - EPS * rr;              // feasibility threshold
            const float adw = rss / rr;
            const float sw  = (bbr[r] - als) / rr;
            const float ratio = (adw > 0.f) ? (sw / fmaxf(adw, 1e-12f)) : INFINITY;
            rmin = fminf(rmin, ratio);
            alr[r] = als; rsr[r] = rss;
        }
        RED64_MIN(rmin);
        if (lane == 0) s_redw[wave] = rmin;
        __syncthreads();
        if (t == 0) {
            float m = s_redw[0];
            #pragma unroll
            for (int w = 1; w < 8; ++w) m = fminf(m, s_redw[w]);
            s_t0 = fmaxf(0.5f * m, 2.0f * EPS);
        }
        __syncthreads();
        const float t0v = s_t0;
        float xi = 0.f;
        if (t < NN) { xi = s_lower[t] + t0v; s_x[t] = xi; }
        float axc0[4];
        #pragma unroll
        for (int r = 0; r < 4; ++r) {
            axc0[r] = alr[r] + t0v * rsr[r];
            if (j == 0) { s_ax[wb + 4 * g + r] = axc0[r]; s_pg[wb + 4 * g + r] = 0.f; }
        }

        // feasibility repair (faithful to module; no-op for these inputs)
        int okf = 1;
        #pragma unroll
        for (int r = 0; r < 4; ++r) okf = okf && (axc0[r] <= cer[r]);
        if (t < NN) okf = okf && (xi >= s_lower[t] + EPS);
        const int feas = __syncthreads_and(okf);
        if (!feas) {
            if (t < NN) s_x[t] = 0.5f * (fmaxf(s_x[t], 0.f) + s_lower[t]);
            __syncthreads();
            float axp[4] = {0.f,0.f,0.f,0.f};
            #pragma unroll
            for (int c = 0; c < 4; ++c) {
                const float4 x4 = ((const float4*)s_x)[j + 16 * c];
                #pragma unroll
                for (int r = 0; r < 4; ++r) {
                    const float4 av = a[r][c];
                    axp[r] += av.x*x4.x + av.y*x4.y + av.z*x4.z + av.w*x4.w;
                }
            }
            #pragma unroll
            for (int r = 0; r < 4; ++r) {
                const float s = red16_add(axp[r]);
                if (j == 0) s_ax[wb + 4 * g + r] = s;     // s_pg stays 0
            }
            __syncthreads();
        }
    }

    // ------------------------------ main loop ------------------------------
    for (int k = 0; k < K_ITER; ++k) {
        // pass 1: ax recurrence + barrier weights + gbar partials.
        float axm[4];                         // live through pass 2's ballots
        {
            const float stp = s_step;
            float wm[4];
            #pragma unroll
            for (int r = 0; r < 4; ++r) {
                const int m = wb + 4 * g + r;
                axm[r] = s_ax[m] - stp * s_pg[m];
                wm[r]  = MU / fmaxf(bbr[r] - axm[r], clr[r]);
            }
            if (j == 0) {
                #pragma unroll
                for (int r = 0; r < 4; ++r) s_ax[wb + 4 * g + r] = axm[r];
            }
            #pragma unroll
            for (int c = 0; c < 4; ++c) {
                float4 gb;
                gb.x = a[0][c].x*wm[0] + a[1][c].x*wm[1] + a[2][c].x*wm[2] + a[3][c].x*wm[3];
                gb.y = a[0][c].y*wm[0] + a[1][c].y*wm[1] + a[2][c].y*wm[2] + a[3][c].y*wm[3];
                gb.z = a[0][c].z*wm[0] + a[1][c].z*wm[1] + a[2][c].z*wm[2] + a[3][c].z*wm[3];
                gb.w = a[0][c].w*wm[0] + a[1][c].w*wm[1] + a[2][c].w*wm[2] + a[3][c].w*wm[3];
                ((float4*)s_p1g[wave * 4 + g])[j + 16 * c] = gb;
            }
        }
        __syncthreads();                                   // sync1

        // grad + n-side line-search mask — pair-split across all 8 waves:
        // lanes (2c,2c+1) of the block each sum 16 partials for col c.
        {
            const int col  = t >> 1;
            const int half = t & 1;
            float gsum = 0.f;
            #pragma unroll
            for (int q = 0; q < 16; ++q) gsum += s_p1g[half * 16 + q][col];
            gsum += __shfl_xor(gsum, 1);
            const float xt = s_x[col];
            const float gr = (xt - s_xraw[col]) + gsum + MU / fmaxf(xt - s_lower[col], 1e-12f);
            if (half == 0) s_grad[col] = gr;
            unsigned mn = 0u;
            const float loe = s_lower[col] + EPS;
            float st = 1.0f;
            #pragma unroll
            for (int l = 0; l < MAX_LS; ++l) {
                if (xt - st * gr >= loe) mn |= (1u << l);
                st *= 0.5f;
            }
            RED64_AND(mn);
            if (lane == 0) atomicAnd(&s_mask, mn);
        }
        __syncthreads();                                   // sync2

        // pass 2: pg = A*grad + fused m-side line-search ballots (vs axm)
        {
            float pg[4] = {0.f,0.f,0.f,0.f};
            #pragma unroll
            for (int c = 0; c < 4; ++c) {
                const float4 g4 = ((const float4*)s_grad)[j + 16 * c];
                #pragma unroll
                for (int r = 0; r < 4; ++r) {
                    const float4 av = a[r][c];
                    pg[r] += av.x*g4.x + av.y*g4.y + av.z*g4.z + av.w*g4.w;
                }
            }
            unsigned mand = 0xFFFFFFFFu;
            #pragma unroll
            for (int r = 0; r < 4; ++r) {
                const float pgs = red16_add(pg[r]);        // all 16 lanes get row sum
                if (j == 0) s_pg[wb + 4 * g + r] = pgs;
                const bool ok0 = (axm[r] - stepj0 * pgs) <= cer[r];              // step j
                const bool ok1 = (axm[r] - (stepj0 * 0x1p-16f) * pgs) <= cer[r]; // step j+16
                const unsigned long long b0 = __ballot(ok0);
                const unsigned long long b1 = __ballot(ok1);
                const unsigned f = ((unsigned)(b0 >> (16 * g)) & 0xFFFFu)
                                 | (((unsigned)(b1 >> (16 * g)) & 0x1FFu) << 16);
                mand &= (f | 0xFE000000u);
            }
            mand &= __shfl_xor(mand, 16);
            mand &= __shfl_xor(mand, 32);
            if (lane == 0) atomicAnd(&s_mask, mand);
        }
        __syncthreads();                                   // sync3 (s_mask final)

        // ---- grid consensus: flag-store + master OR-reduce + broadcast ----
        const unsigned tag = (unsigned)(k + 1) << 25;
        if (p == 0) {
            __builtin_amdgcn_s_setprio(1);                 // master reduce is grid-critical
            unsigned bad;
            if (t == 0) {
                bad = (~s_mask) & FULLMASK;
            } else {
                unsigned v;
                while ((((v = AGLOAD(&wsu[W_FLAG(t)])) >> 25)) != (unsigned)(k + 1))
                    __builtin_amdgcn_s_sleep(1);
                bad = v & FULLMASK;
            }
            RED64_OR(bad);
            if (lane == 0) s_redu[wave] = bad;
            __syncthreads();
            if (t == 0) {
                unsigned orall = 0u;
                #pragma unroll
                for (int w = 0; w < 8; ++w) orall |= s_redu[w];
                const unsigned gm = FULLMASK & ~orall;
                #pragma unroll
                for (int i = 0; i < NBC; ++i)              // bcast ASAP, before sync
                    AGSTORE(&wsu[W_BCAST(i)], tag | gm);
                s_step = gm ? ldexpf(1.0f, -(__ffs(gm) - 1)) : 0.0f;
                s_mask = 0xFFFFFFFFu;                      // re-arm for next iter
            }
            __builtin_amdgcn_s_setprio(0);
            __syncthreads();                               // sync4 (master)
        } else {
            if (t == 0) {
                AGSTORE(&wsu[W_FLAG(p)], tag | ((~s_mask) & FULLMASK));
                s_mask = 0xFFFFFFFFu;                      // re-arm for next iter
                unsigned v;
                while ((((v = AGLOAD(&wsu[W_BCAST(p & (NBC - 1))])) >> 25)) != (unsigned)(k + 1))
                    __builtin_amdgcn_s_sleep(1);
                const unsigned gm = v & FULLMASK;
                s_step = gm ? ldexpf(1.0f, -(__ffs(gm) - 1)) : 0.0f;
            }
            __syncthreads();                               // sync4
        }

        // epilogue: x update only (ax advanced by next pass 1's recurrence)
        if (t < NN) s_x[t] -= s_step * s_grad[t];
        // ordering: s_x writes -> next sync1 -> grad reads; s_ax/s_pg writes
        // (pass1/pass2, before sync3) -> next pass1 reads (after sync4);
        // s_step written before sync4, consumed here and at next pass1 top.
    }

    if (t < NN) out_g[p * NN + t] = fmaxf(s_x[t], 0.0f);
}

// -------------------------------------------------------------- launch ----
extern "C" void kernel_launch(void* const* d_in, const int* in_sizes, int n_in,
                              void* d_out, int out_size, void* d_ws, size_t ws_size,
                              hipStream_t stream) {
    const float* xraw  = (const float*)d_in[0];
    const float* A     = (const float*)d_in[1];
    const float* b     = (const float*)d_in[2];
    const float* lower = (const float*)d_in[3];
    float* out = (float*)d_out;
    unsigned* wsu = (unsigned*)d_ws;

    lbp_ws_init<<<(W_END + 1023) / 1024, 1024, 0, stream>>>(wsu);
    lbp_fused<<<NPROB, NTHR, 0, stream>>>(xraw, A, b, lower, out, wsu);
}